// Round 5
// baseline (708.476 us; speedup 1.0000x reference)
//
#include <hip/hip_runtime.h>
#include <stdint.h>

#define NTHREADS 512
#define C2F 2.8853900817779268f   // 2*log2(e)
#define C1F 1.4426950408889634f   // log2(e)

__device__ __forceinline__ float asflt(uint32_t u) {
    union { uint32_t u; float f; } x; x.u = u; return x.f;
}
__device__ __forceinline__ uint32_t bf16rne(float f) {
    uint32_t u = __float_as_uint(f);
    return (u + 0x7FFFu + ((u >> 16) & 1u)) >> 16;   // high 16 bits as bf16
}

// LDS enc layout: 4 planes, plane q (=u>>2) at byte q*16384 + t*8, holding
// bf16 {u=4q..4q+3} of row t as 2x u32. Lane-stride 8B => 2-way bank alias (free).
__global__ __launch_bounds__(NTHREADS, 4)
void decoder_kernel(const int* __restrict__ nin,
                    const float* __restrict__ enc,     // [B,2048,16]
                    const float* __restrict__ hidden,  // [B,16]
                    const float* __restrict__ w1,      // [16,16]
                    const float* __restrict__ w2k,     // [16,16]
                    const float* __restrict__ w2b,     // [16]
                    const float* __restrict__ w3k,     // [16,1]
                    const float* __restrict__ gruk,    // [16,48]
                    const float* __restrict__ grub,    // [48]
                    const float* __restrict__ dek,     // [16,8]
                    const float* __restrict__ deb,     // [8]
                    float* __restrict__ out)           // [B,S,8]
{
    extern __shared__ char smem[];
    float* F    = (float*)(smem + 65536);
    float* wred = F;            // 128
    float* lred = F + 128;      // 8
    float* Qbuf = F + 136;      // 16
    float* hbuf = F + 152;      // 16
    float* ctxb = F + 168;      // 16
    float* w2bl = F + 184;      // 16
    float* gbzl = F + 200;      // 16
    float* gbhl = F + 216;      // 16
    float* dbl  = F + 232;      // 8
    float* w2l  = F + 240;      // 256
    float* gkzl = F + 496;      // 256
    float* gkhl = F + 752;      // 256
    float* dkl  = F + 1008;     // 128  (end 1136 floats = 4544 B)

    const int tid  = threadIdx.x;
    const int b    = blockIdx.x;
    const int S    = nin[0];
    const int lane = tid & 63;
    const int wv   = tid >> 6;

    // ---- weights -> LDS ----
    if (tid < 256) {
        w2l[tid] = w2k[tid];
        int m = tid >> 4, v = tid & 15;
        gkzl[tid] = gruk[m * 48 + v];
        gkhl[tid] = gruk[m * 48 + 32 + v];
    }
    if (tid < 128) dkl[tid] = dek[tid];
    if (tid < 16) {
        w2bl[tid] = w2b[tid];
        gbzl[tid] = grub[tid];
        gbhl[tid] = grub[32 + tid];
    }
    if (tid < 8) dbl[tid] = deb[tid];

    // ---- enc row -> bf16 LDS (coalesced float4 loads, RNE) ----
    {
        const float4* eg = (const float4*)enc + (size_t)b * 8192;
        #pragma unroll
        for (int i = 0; i < 16; ++i) {
            int f = tid + NTHREADS * i;        // float4 index = t*4 + q
            float4 vv = eg[f];
            int t = f >> 2, q = f & 3;
            uint2 w;
            w.x = bf16rne(vv.x) | (bf16rne(vv.y) << 16);
            w.y = bf16rne(vv.z) | (bf16rne(vv.w) << 16);
            *(uint2*)(smem + q * 16384 + t * 8) = w;
        }
    }
    __syncthreads();

    // ---- E = exp(2*enc@w1) -> bf16 packed in regs.
    // Streams k=0..3 own t_k = tid + 512k. acc[v*4+k]. w1 is wave-uniform (scalar loads).
    float acc[64];
    #pragma unroll
    for (int i = 0; i < 64; ++i) acc[i] = 0.0f;
    #pragma unroll
    for (int u = 0; u < 16; ++u) {
        const char* pb = smem + (u >> 2) * 16384 + (u & 3) * 2;
        float e0 = asflt(((uint32_t)*(const uint16_t*)(pb + (tid          ) * 8)) << 16);
        float e1 = asflt(((uint32_t)*(const uint16_t*)(pb + (tid + 512    ) * 8)) << 16);
        float e2 = asflt(((uint32_t)*(const uint16_t*)(pb + (tid + 1024   ) * 8)) << 16);
        float e3 = asflt(((uint32_t)*(const uint16_t*)(pb + (tid + 1536   ) * 8)) << 16);
        #pragma unroll
        for (int v = 0; v < 16; ++v) {
            float wv1 = w1[u * 16 + v];        // uniform -> SGPR
            acc[v * 4 + 0] = fmaf(e0, wv1, acc[v * 4 + 0]);
            acc[v * 4 + 1] = fmaf(e1, wv1, acc[v * 4 + 1]);
            acc[v * 4 + 2] = fmaf(e2, wv1, acc[v * 4 + 2]);
            acc[v * 4 + 3] = fmaf(e3, wv1, acc[v * 4 + 3]);
        }
    }
    uint32_t Epack[32];                        // Epack[u*2+p]: lo=E(u,2p), hi=E(u,2p+1)
    #pragma unroll
    for (int v = 0; v < 16; ++v) {
        float E0 = __builtin_amdgcn_exp2f(C2F * acc[v * 4 + 0]);
        float E1 = __builtin_amdgcn_exp2f(C2F * acc[v * 4 + 1]);
        float E2 = __builtin_amdgcn_exp2f(C2F * acc[v * 4 + 2]);
        float E3 = __builtin_amdgcn_exp2f(C2F * acc[v * 4 + 3]);
        Epack[v * 2 + 0] = bf16rne(E0) | (bf16rne(E1) << 16);
        Epack[v * 2 + 1] = bf16rne(E2) | (bf16rne(E3) << 16);
    }
    float n3r[16];
    #pragma unroll
    for (int u = 0; u < 16; ++u) n3r[u] = -2.0f * w3k[u];   // uniform

    // ---- initial Q from `hidden` (wave 0) ----
    if (wv == 0) {
        if (lane < 16) hbuf[lane] = hidden[b * 16 + lane];
        int u = lane & 15;
        float q = w2bl[u];
        #pragma unroll
        for (int m = 0; m < 16; ++m) q = fmaf(hbuf[m], w2l[m * 16 + u], q);
        if (lane < 16) Qbuf[u] = __builtin_amdgcn_exp2f(C2F * q);
    }
    __syncthreads();

    for (int s = 0; s < S; ++s) {
        // ---- phase B: p_k = exp(score_k) in registers ----
        float Qr[16];
        #pragma unroll
        for (int u = 0; u < 16; ++u) Qr[u] = Qbuf[u];
        float a0 = 0.f, a1 = 0.f, a2 = 0.f, a3 = 0.f;
        #pragma unroll
        for (int u = 0; u < 16; ++u) {
            uint32_t pA = Epack[u * 2 + 0], pB = Epack[u * 2 + 1];
            float E0 = asflt(pA << 16), E1 = asflt(pA & 0xFFFF0000u);
            float E2 = asflt(pB << 16), E3 = asflt(pB & 0xFFFF0000u);
            float qu = Qr[u], nu = n3r[u];
            a0 = fmaf(nu, __builtin_amdgcn_rcpf(fmaf(E0, qu, 1.0f)), a0);
            a1 = fmaf(nu, __builtin_amdgcn_rcpf(fmaf(E1, qu, 1.0f)), a1);
            a2 = fmaf(nu, __builtin_amdgcn_rcpf(fmaf(E2, qu, 1.0f)), a2);
            a3 = fmaf(nu, __builtin_amdgcn_rcpf(fmaf(E3, qu, 1.0f)), a3);
        }
        float p0 = __builtin_amdgcn_exp2f(C1F * a0);
        float p1 = __builtin_amdgcn_exp2f(C1F * a1);
        float p2 = __builtin_amdgcn_exp2f(C1F * a2);
        float p3 = __builtin_amdgcn_exp2f(C1F * a3);

        // ---- phase C: ctx[v] partials from own t-rows, then wave fold-reduce ----
        float cx[16];
        #pragma unroll
        for (int q = 0; q < 4; ++q) {
            const char* pb = smem + q * 16384;
            uint2 w0 = *(const uint2*)(pb + (tid       ) * 8);
            uint2 w1_ = *(const uint2*)(pb + (tid + 512) * 8);
            uint2 w2_ = *(const uint2*)(pb + (tid + 1024) * 8);
            uint2 w3_ = *(const uint2*)(pb + (tid + 1536) * 8);
            float c0, c1, c2, c3;
            c0 = p0 * asflt(w0.x << 16);          c1 = p0 * asflt(w0.x & 0xFFFF0000u);
            c2 = p0 * asflt(w0.y << 16);          c3 = p0 * asflt(w0.y & 0xFFFF0000u);
            c0 = fmaf(p1, asflt(w1_.x << 16), c0); c1 = fmaf(p1, asflt(w1_.x & 0xFFFF0000u), c1);
            c2 = fmaf(p1, asflt(w1_.y << 16), c2); c3 = fmaf(p1, asflt(w1_.y & 0xFFFF0000u), c3);
            c0 = fmaf(p2, asflt(w2_.x << 16), c0); c1 = fmaf(p2, asflt(w2_.x & 0xFFFF0000u), c1);
            c2 = fmaf(p2, asflt(w2_.y << 16), c2); c3 = fmaf(p2, asflt(w2_.y & 0xFFFF0000u), c3);
            c0 = fmaf(p3, asflt(w3_.x << 16), c0); c1 = fmaf(p3, asflt(w3_.x & 0xFFFF0000u), c1);
            c2 = fmaf(p3, asflt(w3_.y << 16), c2); c3 = fmaf(p3, asflt(w3_.y & 0xFFFF0000u), c3);
            cx[q * 4 + 0] = c0; cx[q * 4 + 1] = c1; cx[q * 4 + 2] = c2; cx[q * 4 + 3] = c3;
        }
        // fold 16 components -> 1 per lane (static indices only; rule #20)
        #pragma unroll
        for (int st = 0; st < 4; ++st) {
            const int half = 8 >> st;
            const int bit = (lane >> st) & 1;
            #pragma unroll
            for (int j = 0; j < half; ++j) {
                float lo = cx[j], hi = cx[half + j];
                float mine  = bit ? hi : lo;
                float other = bit ? lo : hi;
                other = __shfl_xor(other, 1 << st, 64);
                cx[j] = mine + other;
            }
        }
        cx[0] += __shfl_xor(cx[0], 16, 64);
        cx[0] += __shfl_xor(cx[0], 32, 64);
        if (lane < 16) {
            int c = ((lane & 1) << 3) | ((lane & 2) << 1) | ((lane & 4) >> 1) | ((lane & 8) >> 3);
            wred[wv * 16 + c] = cx[0];
        }
        float lp = (p0 + p1) + (p2 + p3);
        #pragma unroll
        for (int m = 1; m < 64; m <<= 1) lp += __shfl_xor(lp, m, 64);
        if (lane == 0) lred[wv] = lp;
        __syncthreads();

        // ---- phase D (wave 0): ctx, GRU(h0=0), dense out, next Q ----
        if (wv == 0) {
            int v = lane & 15;
            float l = 0.f;
            #pragma unroll
            for (int m = 0; m < 8; ++m) l += lred[m];
            float ctx = 0.f;
            #pragma unroll
            for (int m = 0; m < 8; ++m) ctx += wred[m * 16 + v];
            ctx *= __builtin_amdgcn_rcpf(l);
            if (lane < 16) ctxb[v] = ctx;
            float xz = gbzl[v], xh = gbhl[v];
            #pragma unroll
            for (int m = 0; m < 16; ++m) {
                float cm = ctxb[m];
                xz = fmaf(cm, gkzl[m * 16 + v], xz);
                xh = fmaf(cm, gkhl[m * 16 + v], xh);
            }
            float z  = __builtin_amdgcn_rcpf(1.0f + __builtin_amdgcn_exp2f(-C1F * xz));
            float eh = __builtin_amdgcn_exp2f(C2F * xh);
            float hh = fmaf(-2.0f, __builtin_amdgcn_rcpf(eh + 1.0f), 1.0f);
            float hn = (1.0f - z) * hh;
            if (lane < 16) hbuf[v] = hn;
            int o = lane & 7;
            float ov = dbl[o];
            #pragma unroll
            for (int u = 0; u < 16; ++u) ov = fmaf(hbuf[u], dkl[u * 8 + o], ov);
            if (lane < 8) out[(size_t)b * (S * 8) + s * 8 + o] = ov;
            float q = w2bl[v];
            #pragma unroll
            for (int m = 0; m < 16; ++m) q = fmaf(hbuf[m], w2l[m * 16 + v], q);
            if (lane < 16) Qbuf[v] = __builtin_amdgcn_exp2f(C2F * q);
        }
        __syncthreads();
    }
}

#define SMEM_BYTES 70144

extern "C" void kernel_launch(void* const* d_in, const int* in_sizes, int n_in,
                              void* d_out, int out_size, void* d_ws, size_t ws_size,
                              hipStream_t stream) {
    (void)in_sizes; (void)n_in; (void)d_ws; (void)ws_size; (void)out_size;
    const int*   nin    = (const int*)d_in[0];
    const float* enc    = (const float*)d_in[1];
    const float* hidden = (const float*)d_in[2];
    const float* w1     = (const float*)d_in[3];
    const float* w2k    = (const float*)d_in[4];
    const float* w2b    = (const float*)d_in[5];
    const float* w3k    = (const float*)d_in[6];
    // d_in[7] = w3_b (constant shift, cancels in softmax); d_in[9] = gru_rk (dead, h0=0)
    const float* gruk   = (const float*)d_in[8];
    const float* grub   = (const float*)d_in[10];
    const float* dek    = (const float*)d_in[11];
    const float* deb    = (const float*)d_in[12];
    float* outp = (float*)d_out;

    hipFuncSetAttribute(reinterpret_cast<const void*>(&decoder_kernel),
                        hipFuncAttributeMaxDynamicSharedMemorySize, SMEM_BYTES);
    decoder_kernel<<<2048, NTHREADS, SMEM_BYTES, stream>>>(
        nin, enc, hidden, w1, w2k, w2b, w3k, gruk, grub, dek, deb, outp);
}

// Round 6
// 689.362 us; speedup vs baseline: 1.0277x; 1.0277x over previous
//
#include <hip/hip_runtime.h>
#include <stdint.h>

#define NTHREADS 512
#define C2F 2.8853900817779268f   // 2*log2(e)
#define C1F 1.4426950408889634f   // log2(e)

__device__ __forceinline__ float asflt(uint32_t u) {
    union { uint32_t u; float f; } x; x.u = u; return x.f;
}
__device__ __forceinline__ uint32_t bf16rne(float f) {
    uint32_t u = __float_as_uint(f);
    return (u + 0x7FFFu + ((u >> 16) & 1u)) >> 16;   // high 16 bits as bf16
}

// LDS enc layout: 4 planes, plane q (=u>>2) at byte q*16384 + t*8, holding
// bf16 {u=4q..4q+3} of row t as 2x u32. Lane-stride 8B => 2-way bank alias (free).
// amdgpu_waves_per_eu(4,4): LDS (70KB, dynamic -> invisible to compiler) caps us
// at 2 blocks/CU = 4 waves/EU anyway; without this the compiler targeted 8/EU,
// allocated 64 VGPRs and spilled ~160B/thread (r5: WRITE_SIZE 158MB/dispatch).
__global__ __launch_bounds__(NTHREADS)
__attribute__((amdgpu_waves_per_eu(4, 4)))
void decoder_kernel(const int* __restrict__ nin,
                    const float* __restrict__ enc,     // [B,2048,16]
                    const float* __restrict__ hidden,  // [B,16]
                    const float* __restrict__ w1,      // [16,16]
                    const float* __restrict__ w2k,     // [16,16]
                    const float* __restrict__ w2b,     // [16]
                    const float* __restrict__ w3k,     // [16,1]
                    const float* __restrict__ gruk,    // [16,48]
                    const float* __restrict__ grub,    // [48]
                    const float* __restrict__ dek,     // [16,8]
                    const float* __restrict__ deb,     // [8]
                    float* __restrict__ out)           // [B,S,8]
{
    extern __shared__ char smem[];
    float* F    = (float*)(smem + 65536);
    float* wred = F;            // 128
    float* lred = F + 128;      // 8
    float* Qbuf = F + 136;      // 16
    float* hbuf = F + 152;      // 16
    float* ctxb = F + 168;      // 16
    float* w2bl = F + 184;      // 16
    float* gbzl = F + 200;      // 16
    float* gbhl = F + 216;      // 16
    float* dbl  = F + 232;      // 8
    float* w2l  = F + 240;      // 256
    float* gkzl = F + 496;      // 256
    float* gkhl = F + 752;      // 256
    float* dkl  = F + 1008;     // 128  (end 1136 floats = 4544 B)

    const int tid  = threadIdx.x;
    const int b    = blockIdx.x;
    const int S    = nin[0];
    const int lane = tid & 63;
    const int wv   = tid >> 6;

    // ---- weights -> LDS ----
    if (tid < 256) {
        w2l[tid] = w2k[tid];
        int m = tid >> 4, v = tid & 15;
        gkzl[tid] = gruk[m * 48 + v];
        gkhl[tid] = gruk[m * 48 + 32 + v];
    }
    if (tid < 128) dkl[tid] = dek[tid];
    if (tid < 16) {
        w2bl[tid] = w2b[tid];
        gbzl[tid] = grub[tid];
        gbhl[tid] = grub[32 + tid];
    }
    if (tid < 8) dbl[tid] = deb[tid];

    // ---- enc row -> bf16 LDS (coalesced float4 loads, RNE) ----
    {
        const float4* eg = (const float4*)enc + (size_t)b * 8192;
        #pragma unroll
        for (int i = 0; i < 16; ++i) {
            int f = tid + NTHREADS * i;        // float4 index = t*4 + q
            float4 vv = eg[f];
            int t = f >> 2, q = f & 3;
            uint2 w;
            w.x = bf16rne(vv.x) | (bf16rne(vv.y) << 16);
            w.y = bf16rne(vv.z) | (bf16rne(vv.w) << 16);
            *(uint2*)(smem + q * 16384 + t * 8) = w;
        }
    }
    __syncthreads();

    // ---- E = exp(2*enc@w1) -> bf16 packed in regs, one t-stream at a time.
    // Stream k owns t_k = tid + 512k. Peak live: Epack(<=32) + acc(16) + temps.
    // Epack[u*2+p]: lo = E(u, t=tid+512*(2p)), hi = E(u, t=tid+512*(2p+1)).
    uint32_t Epack[32];
    #pragma unroll
    for (int k = 0; k < 4; ++k) {
        const int t = tid + 512 * k;
        float acc[16];
        #pragma unroll
        for (int v = 0; v < 16; ++v) acc[v] = 0.0f;
        #pragma unroll
        for (int q = 0; q < 4; ++q) {
            uint2 w = *(const uint2*)(smem + q * 16384 + t * 8);
            float e0 = asflt(w.x << 16), e1 = asflt(w.x & 0xFFFF0000u);
            float e2 = asflt(w.y << 16), e3 = asflt(w.y & 0xFFFF0000u);
            #pragma unroll
            for (int v = 0; v < 16; ++v) {
                acc[v] = fmaf(e0, w1[(4 * q + 0) * 16 + v], acc[v]);
                acc[v] = fmaf(e1, w1[(4 * q + 1) * 16 + v], acc[v]);
                acc[v] = fmaf(e2, w1[(4 * q + 2) * 16 + v], acc[v]);
                acc[v] = fmaf(e3, w1[(4 * q + 3) * 16 + v], acc[v]);
            }
        }
        #pragma unroll
        for (int v = 0; v < 16; ++v) {
            uint32_t h = bf16rne(__builtin_amdgcn_exp2f(C2F * acc[v]));
            if ((k & 1) == 0) Epack[v * 2 + (k >> 1)] = h;
            else              Epack[v * 2 + (k >> 1)] |= h << 16;
        }
    }
    float n3r[16];
    #pragma unroll
    for (int u = 0; u < 16; ++u) n3r[u] = -2.0f * w3k[u];   // uniform -> SGPR-friendly

    // ---- initial Q from `hidden` (wave 0) ----
    if (wv == 0) {
        if (lane < 16) hbuf[lane] = hidden[b * 16 + lane];
        int u = lane & 15;
        float q = w2bl[u];
        #pragma unroll
        for (int m = 0; m < 16; ++m) q = fmaf(hbuf[m], w2l[m * 16 + u], q);
        if (lane < 16) Qbuf[u] = __builtin_amdgcn_exp2f(C2F * q);
    }
    __syncthreads();

    for (int s = 0; s < S; ++s) {
        // ---- phase B: p_k = exp(score_k) in registers ----
        float Qr[16];
        #pragma unroll
        for (int u = 0; u < 16; ++u) Qr[u] = Qbuf[u];
        float a0 = 0.f, a1 = 0.f, a2 = 0.f, a3 = 0.f;
        #pragma unroll
        for (int u = 0; u < 16; ++u) {
            uint32_t pA = Epack[u * 2 + 0], pB = Epack[u * 2 + 1];
            float E0 = asflt(pA << 16), E1 = asflt(pA & 0xFFFF0000u);
            float E2 = asflt(pB << 16), E3 = asflt(pB & 0xFFFF0000u);
            float qu = Qr[u], nu = n3r[u];
            a0 = fmaf(nu, __builtin_amdgcn_rcpf(fmaf(E0, qu, 1.0f)), a0);
            a1 = fmaf(nu, __builtin_amdgcn_rcpf(fmaf(E1, qu, 1.0f)), a1);
            a2 = fmaf(nu, __builtin_amdgcn_rcpf(fmaf(E2, qu, 1.0f)), a2);
            a3 = fmaf(nu, __builtin_amdgcn_rcpf(fmaf(E3, qu, 1.0f)), a3);
        }
        float p0 = __builtin_amdgcn_exp2f(C1F * a0);
        float p1 = __builtin_amdgcn_exp2f(C1F * a1);
        float p2 = __builtin_amdgcn_exp2f(C1F * a2);
        float p3 = __builtin_amdgcn_exp2f(C1F * a3);

        // ---- phase C: ctx[v] partials from own t-rows, then wave fold-reduce ----
        float cx[16];
        #pragma unroll
        for (int q = 0; q < 4; ++q) {
            const char* pb = smem + q * 16384;
            uint2 w0 = *(const uint2*)(pb + (tid       ) * 8);
            uint2 w1_ = *(const uint2*)(pb + (tid + 512) * 8);
            uint2 w2_ = *(const uint2*)(pb + (tid + 1024) * 8);
            uint2 w3_ = *(const uint2*)(pb + (tid + 1536) * 8);
            float c0, c1, c2, c3;
            c0 = p0 * asflt(w0.x << 16);          c1 = p0 * asflt(w0.x & 0xFFFF0000u);
            c2 = p0 * asflt(w0.y << 16);          c3 = p0 * asflt(w0.y & 0xFFFF0000u);
            c0 = fmaf(p1, asflt(w1_.x << 16), c0); c1 = fmaf(p1, asflt(w1_.x & 0xFFFF0000u), c1);
            c2 = fmaf(p1, asflt(w1_.y << 16), c2); c3 = fmaf(p1, asflt(w1_.y & 0xFFFF0000u), c3);
            c0 = fmaf(p2, asflt(w2_.x << 16), c0); c1 = fmaf(p2, asflt(w2_.x & 0xFFFF0000u), c1);
            c2 = fmaf(p2, asflt(w2_.y << 16), c2); c3 = fmaf(p2, asflt(w2_.y & 0xFFFF0000u), c3);
            c0 = fmaf(p3, asflt(w3_.x << 16), c0); c1 = fmaf(p3, asflt(w3_.x & 0xFFFF0000u), c1);
            c2 = fmaf(p3, asflt(w3_.y << 16), c2); c3 = fmaf(p3, asflt(w3_.y & 0xFFFF0000u), c3);
            cx[q * 4 + 0] = c0; cx[q * 4 + 1] = c1; cx[q * 4 + 2] = c2; cx[q * 4 + 3] = c3;
        }
        // fold 16 components -> 1 per lane (static indices only; rule #20)
        #pragma unroll
        for (int st = 0; st < 4; ++st) {
            const int half = 8 >> st;
            const int bit = (lane >> st) & 1;
            #pragma unroll
            for (int j = 0; j < half; ++j) {
                float lo = cx[j], hi = cx[half + j];
                float mine  = bit ? hi : lo;
                float other = bit ? lo : hi;
                other = __shfl_xor(other, 1 << st, 64);
                cx[j] = mine + other;
            }
        }
        cx[0] += __shfl_xor(cx[0], 16, 64);
        cx[0] += __shfl_xor(cx[0], 32, 64);
        if (lane < 16) {
            int c = ((lane & 1) << 3) | ((lane & 2) << 1) | ((lane & 4) >> 1) | ((lane & 8) >> 3);
            wred[wv * 16 + c] = cx[0];
        }
        float lp = (p0 + p1) + (p2 + p3);
        #pragma unroll
        for (int m = 1; m < 64; m <<= 1) lp += __shfl_xor(lp, m, 64);
        if (lane == 0) lred[wv] = lp;
        __syncthreads();

        // ---- phase D (wave 0): ctx, GRU(h0=0), dense out, next Q ----
        if (wv == 0) {
            int v = lane & 15;
            float l = 0.f;
            #pragma unroll
            for (int m = 0; m < 8; ++m) l += lred[m];
            float ctx = 0.f;
            #pragma unroll
            for (int m = 0; m < 8; ++m) ctx += wred[m * 16 + v];
            ctx *= __builtin_amdgcn_rcpf(l);
            if (lane < 16) ctxb[v] = ctx;
            float xz = gbzl[v], xh = gbhl[v];
            #pragma unroll
            for (int m = 0; m < 16; ++m) {
                float cm = ctxb[m];
                xz = fmaf(cm, gkzl[m * 16 + v], xz);
                xh = fmaf(cm, gkhl[m * 16 + v], xh);
            }
            float z  = __builtin_amdgcn_rcpf(1.0f + __builtin_amdgcn_exp2f(-C1F * xz));
            float eh = __builtin_amdgcn_exp2f(C2F * xh);
            float hh = fmaf(-2.0f, __builtin_amdgcn_rcpf(eh + 1.0f), 1.0f);
            float hn = (1.0f - z) * hh;
            if (lane < 16) hbuf[v] = hn;
            int o = lane & 7;
            float ov = dbl[o];
            #pragma unroll
            for (int u = 0; u < 16; ++u) ov = fmaf(hbuf[u], dkl[u * 8 + o], ov);
            if (lane < 8) out[(size_t)b * (S * 8) + s * 8 + o] = ov;
            float q = w2bl[v];
            #pragma unroll
            for (int m = 0; m < 16; ++m) q = fmaf(hbuf[m], w2l[m * 16 + v], q);
            if (lane < 16) Qbuf[v] = __builtin_amdgcn_exp2f(C2F * q);
        }
        __syncthreads();
    }
}

#define SMEM_BYTES 70144

extern "C" void kernel_launch(void* const* d_in, const int* in_sizes, int n_in,
                              void* d_out, int out_size, void* d_ws, size_t ws_size,
                              hipStream_t stream) {
    (void)in_sizes; (void)n_in; (void)d_ws; (void)ws_size; (void)out_size;
    const int*   nin    = (const int*)d_in[0];
    const float* enc    = (const float*)d_in[1];
    const float* hidden = (const float*)d_in[2];
    const float* w1     = (const float*)d_in[3];
    const float* w2k    = (const float*)d_in[4];
    const float* w2b    = (const float*)d_in[5];
    const float* w3k    = (const float*)d_in[6];
    // d_in[7] = w3_b (constant shift, cancels in softmax); d_in[9] = gru_rk (dead, h0=0)
    const float* gruk   = (const float*)d_in[8];
    const float* grub   = (const float*)d_in[10];
    const float* dek    = (const float*)d_in[11];
    const float* deb    = (const float*)d_in[12];
    float* outp = (float*)d_out;

    hipFuncSetAttribute(reinterpret_cast<const void*>(&decoder_kernel),
                        hipFuncAttributeMaxDynamicSharedMemorySize, SMEM_BYTES);
    decoder_kernel<<<2048, NTHREADS, SMEM_BYTES, stream>>>(
        nin, enc, hidden, w1, w2k, w2b, w3k, gruk, grub, dek, deb, outp);
}